// Round 1
// baseline (193.218 us; speedup 1.0000x reference)
//
#include <hip/hip_runtime.h>

#define THREADS 256

// ---------------------------------------------------------------------------
// Kernel A: in-side contraction  x[N,4096] -> u3[N,512]
//   u1[d,e,n6] = sum_f x[d,e,f] * f5[f,n6]
//   u2[d,m,n6] = sum_e u1[d,e,n6] * f4[e,m]
//   u3[l,m,n6] = sum_d u2[d,m,n6] * f3[d,l]
// One block per batch row. x chunk lives in VGPRs (thread t owns de=t).
// ---------------------------------------------------------------------------
__global__ __launch_bounds__(THREADS) void k_in_contract(
    const float* __restrict__ x,
    const float* __restrict__ f3, const float* __restrict__ f4,
    const float* __restrict__ f5,
    float* __restrict__ u3, int N)
{
    const int n = blockIdx.x;
    const int t = threadIdx.x;

    __shared__ float fs[256];        // f3 [0..128) | f4 [128..256)
    __shared__ float u1s[256 * 9];   // [de][n6], pad 9 -> 2-way max
    __shared__ float u2s[128 * 9];   // [d*8+m][n6], pad 9

    if (t < 128) { fs[t] = f3[t]; fs[128 + t] = f4[t]; }

    // x chunk for de = t: 16 consecutive floats, 4x float4 (coalesced 16B/lane)
    float xv[16];
    {
        const float4* xr = (const float4*)(x + (size_t)n * 4096 + t * 16);
        float4 a0 = xr[0], a1 = xr[1], a2 = xr[2], a3 = xr[3];
        xv[0]=a0.x; xv[1]=a0.y; xv[2]=a0.z; xv[3]=a0.w;
        xv[4]=a1.x; xv[5]=a1.y; xv[6]=a1.z; xv[7]=a1.w;
        xv[8]=a2.x; xv[9]=a2.y; xv[10]=a2.z; xv[11]=a2.w;
        xv[12]=a3.x; xv[13]=a3.y; xv[14]=a3.z; xv[15]=a3.w;
    }

    // u1 stage: f5[f*8+n6] is lane-uniform (constant index, kernel-arg ptr)
    // -> compiler emits scalar loads, FMA with SGPR operand.
    float acc8[8];
    #pragma unroll
    for (int q = 0; q < 8; ++q) acc8[q] = 0.f;
    #pragma unroll
    for (int f = 0; f < 16; ++f) {
        const float xf = xv[f];
        #pragma unroll
        for (int n6 = 0; n6 < 8; ++n6)
            acc8[n6] = fmaf(xf, f5[f*8 + n6], acc8[n6]);
    }
    __syncthreads();   // fs ready (needed below); also orders u1s writes
    #pragma unroll
    for (int n6 = 0; n6 < 8; ++n6) u1s[t*9 + n6] = acc8[n6];
    __syncthreads();

    // u2 stage: thread -> (d = t>>4, m = (t>>1)&7, h = t&1), n6 = 4h..4h+3
    {
        const int d = t >> 4, m = (t >> 1) & 7, h = t & 1;
        float fr[16];
        #pragma unroll
        for (int e = 0; e < 16; ++e) fr[e] = fs[128 + e*8 + m];
        float a4[4] = {0.f, 0.f, 0.f, 0.f};
        #pragma unroll
        for (int e = 0; e < 16; ++e) {
            const int base = (d*16 + e)*9 + h*4;
            #pragma unroll
            for (int q = 0; q < 4; ++q)
                a4[q] = fmaf(u1s[base + q], fr[e], a4[q]);
        }
        #pragma unroll
        for (int q = 0; q < 4; ++q) u2s[(d*8 + m)*9 + h*4 + q] = a4[q];
    }
    __syncthreads();

    // u3 stage: thread -> (l = t>>5, m = (t>>2)&7, h = t&3), n6 = 2h, 2h+1
    {
        const int l = t >> 5, m = (t >> 2) & 7, h = t & 3;
        float fr[16];
        #pragma unroll
        for (int d = 0; d < 16; ++d) fr[d] = fs[d*8 + l];
        float a2[2] = {0.f, 0.f};
        #pragma unroll
        for (int d = 0; d < 16; ++d) {
            const int base = (d*8 + m)*9 + h*2;
            a2[0] = fmaf(u2s[base],     fr[d], a2[0]);
            a2[1] = fmaf(u2s[base + 1], fr[d], a2[1]);
        }
        float2 o2 = make_float2(a2[0], a2[1]);
        *(float2*)(u3 + (size_t)n*512 + l*64 + m*8 + h*2) = o2;
    }
}

// ---------------------------------------------------------------------------
// Kernel B: core GEMM  v[n,p] = sum_q u3[n,q] * core[p*512+q]
// M=N, Nout=512, K=512. BM=64, BN=64, BK=32, 256 threads, 4x4 microtile.
// Grid: (N/64, 8) = 512 blocks (2/CU).
// ---------------------------------------------------------------------------
#define BM 64
#define BN 64
#define BK 32
#define PADB 36   // 36*4=144 bytes, 16B-aligned rows; strided reads -> <=2-way

__global__ __launch_bounds__(THREADS) void k_core_gemm(
    const float* __restrict__ u3, const float* __restrict__ core,
    float* __restrict__ v, int N)
{
    __shared__ float As[BM * PADB];
    __shared__ float Bs[BN * PADB];
    const int t   = threadIdx.x;
    const int bm0 = blockIdx.x * BM;
    const int bn0 = blockIdx.y * BN;
    const int tr  = t >> 4;    // 0..15
    const int tc  = t & 15;    // 0..15

    float acc[4][4] = {};

    for (int k0 = 0; k0 < 512; k0 += BK) {
        #pragma unroll
        for (int p = 0; p < 2; ++p) {
            const int f4id = p * 256 + t;      // 0..511
            const int r    = f4id >> 3;        // 0..63 (8 float4 per row)
            const int c4   = (f4id & 7) << 2;  // 0,4,...,28
            const int arow = bm0 + r;
            float4 av = (arow < N)
                ? *(const float4*)(u3 + (size_t)arow*512 + k0 + c4)
                : make_float4(0.f, 0.f, 0.f, 0.f);
            *(float4*)(As + r*PADB + c4) = av;
            float4 bv = *(const float4*)(core + (size_t)(bn0 + r)*512 + k0 + c4);
            *(float4*)(Bs + r*PADB + c4) = bv;
        }
        __syncthreads();
        #pragma unroll
        for (int k = 0; k < BK; ++k) {
            float a[4], b[4];
            #pragma unroll
            for (int i = 0; i < 4; ++i) a[i] = As[(tr + 16*i)*PADB + k];
            #pragma unroll
            for (int j = 0; j < 4; ++j) b[j] = Bs[(tc + 16*j)*PADB + k];
            #pragma unroll
            for (int i = 0; i < 4; ++i)
                #pragma unroll
                for (int j = 0; j < 4; ++j)
                    acc[i][j] = fmaf(a[i], b[j], acc[i][j]);
        }
        __syncthreads();
    }

    #pragma unroll
    for (int i = 0; i < 4; ++i) {
        const int row = bm0 + tr + 16*i;
        if (row < N) {
            #pragma unroll
            for (int j = 0; j < 4; ++j)
                v[(size_t)row*512 + bn0 + tc + 16*j] = acc[i][j];
        }
    }
}

// ---------------------------------------------------------------------------
// Kernel C: out-side expansion  v[N,512] -> y[N,4096] (+bias)
//   w1[a,j,k] = sum_i v[i,j,k] * f0[a,i]
//   w2[a,b,k] = sum_j w1[a,j,k] * f1[b,j]
//   y[a,b,c]  = sum_k w2[a,b,k] * f2[c,k] + bias[a,b,c]
// One block per batch row.
// ---------------------------------------------------------------------------
__global__ __launch_bounds__(THREADS) void k_out_expand(
    const float* __restrict__ v,
    const float* __restrict__ f0, const float* __restrict__ f1,
    const float* __restrict__ f2, const float* __restrict__ bias,
    float* __restrict__ y, int N)
{
    const int n = blockIdx.x;
    const int t = threadIdx.x;

    __shared__ float fs[256];        // f0 [0..128) | f1 [128..256)
    __shared__ float vs[512];
    __shared__ float w1s[128 * 9];   // [a*8+j][k], pad 9
    __shared__ float w2s[256 * 9];   // [a*16+b][k], pad 9

    if (t < 128) { fs[t] = f0[t]; fs[128 + t] = f1[t]; }
    if (t < 128) ((float4*)vs)[t] = ((const float4*)(v + (size_t)n*512))[t];
    __syncthreads();

    // w1 stage: thread -> (a = t>>4, j = (t>>1)&7, h = t&1), k = 4h..4h+3
    {
        const int a = t >> 4, j = (t >> 1) & 7, h = t & 1;
        float fr[8];
        #pragma unroll
        for (int i = 0; i < 8; ++i) fr[i] = fs[a*8 + i];
        float a4[4] = {0.f, 0.f, 0.f, 0.f};
        #pragma unroll
        for (int i = 0; i < 8; ++i) {
            const int base = i*64 + j*8 + h*4;
            #pragma unroll
            for (int q = 0; q < 4; ++q)
                a4[q] = fmaf(vs[base + q], fr[i], a4[q]);
        }
        #pragma unroll
        for (int q = 0; q < 4; ++q) w1s[(a*8 + j)*9 + h*4 + q] = a4[q];
    }
    __syncthreads();

    // w2 stage: thread -> (a = t>>4, b = t&15), all k
    {
        const int a = t >> 4, b = t & 15;
        float fr[8];
        #pragma unroll
        for (int j = 0; j < 8; ++j) fr[j] = fs[128 + b*8 + j];
        float a8[8] = {0.f,0.f,0.f,0.f,0.f,0.f,0.f,0.f};
        #pragma unroll
        for (int j = 0; j < 8; ++j) {
            const int base = (a*8 + j)*9;
            const float fj = fr[j];
            #pragma unroll
            for (int k = 0; k < 8; ++k)
                a8[k] = fmaf(w1s[base + k], fj, a8[k]);
        }
        #pragma unroll
        for (int k = 0; k < 8; ++k) w2s[(a*16 + b)*9 + k] = a8[k];
    }
    __syncthreads();

    // y stage: thread -> (a = t>>4, b = t&15), c = 0..15
    {
        const int a = t >> 4, b = t & 15;
        float wr[8];
        #pragma unroll
        for (int k = 0; k < 8; ++k) wr[k] = w2s[(a*16 + b)*9 + k];

        const int obase = a*256 + b*16;   // == t*16
        // bias: 16 consecutive floats per thread -> 4x float4
        float4 b4[4];
        {
            const float4* bp = (const float4*)(bias + obase);
            b4[0] = bp[0]; b4[1] = bp[1]; b4[2] = bp[2]; b4[3] = bp[3];
        }
        float yv[16];
        #pragma unroll
        for (int q = 0; q < 4; ++q) {
            yv[q*4+0] = b4[q].x; yv[q*4+1] = b4[q].y;
            yv[q*4+2] = b4[q].z; yv[q*4+3] = b4[q].w;
        }
        #pragma unroll
        for (int c = 0; c < 16; ++c) {
            float s = yv[c];
            #pragma unroll
            for (int k = 0; k < 8; ++k)
                s = fmaf(wr[k], f2[c*8 + k], s);   // f2 lane-uniform -> s_load
            yv[c] = s;
        }
        float4* o = (float4*)(y + (size_t)n*4096 + obase);
        #pragma unroll
        for (int q = 0; q < 4; ++q)
            o[q] = make_float4(yv[q*4+0], yv[q*4+1], yv[q*4+2], yv[q*4+3]);
    }
}

// ---------------------------------------------------------------------------
extern "C" void kernel_launch(void* const* d_in, const int* in_sizes, int n_in,
                              void* d_out, int out_size, void* d_ws, size_t ws_size,
                              hipStream_t stream)
{
    const float* x    = (const float*)d_in[0];
    const float* core = (const float*)d_in[1];
    const float* f0   = (const float*)d_in[2];
    const float* f1   = (const float*)d_in[3];
    const float* f2   = (const float*)d_in[4];
    const float* f3   = (const float*)d_in[5];
    const float* f4   = (const float*)d_in[6];
    const float* f5   = (const float*)d_in[7];
    const float* bias = (const float*)d_in[8];
    float* y = (float*)d_out;

    const int N = in_sizes[0] / 4096;

    // workspace: u3 [N,512] | v [N,512]  (16 MB total at N=4096)
    float* u3 = (float*)d_ws;
    float* v  = u3 + (size_t)N * 512;

    k_in_contract<<<N, THREADS, 0, stream>>>(x, f3, f4, f5, u3, N);
    dim3 gb((N + BM - 1) / BM, 512 / BN);
    k_core_gemm<<<gb, THREADS, 0, stream>>>(u3, core, v, N);
    k_out_expand<<<N, THREADS, 0, stream>>>(v, f0, f1, f2, bias, y, N);
}

// Round 2
// 163.493 us; speedup vs baseline: 1.1818x; 1.1818x over previous
//
#include <hip/hip_runtime.h>

#define THREADS 256

typedef __attribute__((ext_vector_type(8))) short bf16x8;
typedef __attribute__((ext_vector_type(4))) float f32x4;

// fp32 -> bf16 with round-to-nearest-even (matches HW convert)
__device__ inline unsigned short f2bf(float f) {
    union { float f; unsigned int u; } v; v.f = f;
    unsigned int r = v.u + 0x7fffu + ((v.u >> 16) & 1u);
    return (unsigned short)(r >> 16);
}

// ---------------------------------------------------------------------------
// Kernel A: in-side contraction  x[N,4096] -> u3b[N,512] (bf16)
//   u1[d,e,n6] = sum_f x[d,e,f] * f5[f,n6]
//   u2[d,m,n6] = sum_e u1[d,e,n6] * f4[e,m]
//   u3[l,m,n6] = sum_d u2[d,m,n6] * f3[d,l]
// One block per batch row. x chunk lives in VGPRs (thread t owns de=t).
// ---------------------------------------------------------------------------
__global__ __launch_bounds__(THREADS) void k_in_contract(
    const float* __restrict__ x,
    const float* __restrict__ f3, const float* __restrict__ f4,
    const float* __restrict__ f5,
    unsigned short* __restrict__ u3b, int N)
{
    const int n = blockIdx.x;
    const int t = threadIdx.x;

    __shared__ float fs[256];        // f3 [0..128) | f4 [128..256)
    __shared__ float u1s[256 * 9];   // [de][n6], pad 9 -> 2-way max
    __shared__ float u2s[128 * 9];   // [d*8+m][n6], pad 9

    if (t < 128) { fs[t] = f3[t]; fs[128 + t] = f4[t]; }

    // x chunk for de = t: 16 consecutive floats, 4x float4
    float xv[16];
    {
        const float4* xr = (const float4*)(x + (size_t)n * 4096 + t * 16);
        float4 a0 = xr[0], a1 = xr[1], a2 = xr[2], a3 = xr[3];
        xv[0]=a0.x; xv[1]=a0.y; xv[2]=a0.z; xv[3]=a0.w;
        xv[4]=a1.x; xv[5]=a1.y; xv[6]=a1.z; xv[7]=a1.w;
        xv[8]=a2.x; xv[9]=a2.y; xv[10]=a2.z; xv[11]=a2.w;
        xv[12]=a3.x; xv[13]=a3.y; xv[14]=a3.z; xv[15]=a3.w;
    }

    // u1 stage: f5[f*8+n6] is lane-uniform -> scalar loads
    float acc8[8];
    #pragma unroll
    for (int q = 0; q < 8; ++q) acc8[q] = 0.f;
    #pragma unroll
    for (int f = 0; f < 16; ++f) {
        const float xf = xv[f];
        #pragma unroll
        for (int n6 = 0; n6 < 8; ++n6)
            acc8[n6] = fmaf(xf, f5[f*8 + n6], acc8[n6]);
    }
    __syncthreads();
    #pragma unroll
    for (int n6 = 0; n6 < 8; ++n6) u1s[t*9 + n6] = acc8[n6];
    __syncthreads();

    // u2 stage: thread -> (d = t>>4, m = (t>>1)&7, h = t&1), n6 = 4h..4h+3
    {
        const int d = t >> 4, m = (t >> 1) & 7, h = t & 1;
        float fr[16];
        #pragma unroll
        for (int e = 0; e < 16; ++e) fr[e] = fs[128 + e*8 + m];
        float a4[4] = {0.f, 0.f, 0.f, 0.f};
        #pragma unroll
        for (int e = 0; e < 16; ++e) {
            const int base = (d*16 + e)*9 + h*4;
            #pragma unroll
            for (int q = 0; q < 4; ++q)
                a4[q] = fmaf(u1s[base + q], fr[e], a4[q]);
        }
        #pragma unroll
        for (int q = 0; q < 4; ++q) u2s[(d*8 + m)*9 + h*4 + q] = a4[q];
    }
    __syncthreads();

    // u3 stage: thread -> (l = t>>5, m = (t>>2)&7, h = t&3); offset = 2t
    {
        const int l = t >> 5, m = (t >> 2) & 7, h = t & 3;
        float fr[16];
        #pragma unroll
        for (int d = 0; d < 16; ++d) fr[d] = fs[d*8 + l];
        float a2[2] = {0.f, 0.f};
        #pragma unroll
        for (int d = 0; d < 16; ++d) {
            const int base = (d*8 + m)*9 + h*2;
            a2[0] = fmaf(u2s[base],     fr[d], a2[0]);
            a2[1] = fmaf(u2s[base + 1], fr[d], a2[1]);
        }
        // pack 2 bf16 -> one dword, coalesced (uint index = t)
        unsigned int pk = (unsigned int)f2bf(a2[0]) |
                          ((unsigned int)f2bf(a2[1]) << 16);
        ((unsigned int*)u3b)[(size_t)n * 256 + t] = pk;
    }
}

// ---------------------------------------------------------------------------
// core fp32 [512,512] -> bf16. 256 blocks x 256 thr x 4 elems.
// ---------------------------------------------------------------------------
__global__ __launch_bounds__(THREADS) void k_convert_core(
    const float* __restrict__ core, unsigned short* __restrict__ coreb)
{
    const int i = blockIdx.x * THREADS + threadIdx.x;   // 0..65535 (float4 id)
    float4 c = ((const float4*)core)[i];
    ushort4 o;
    o.x = f2bf(c.x); o.y = f2bf(c.y); o.z = f2bf(c.z); o.w = f2bf(c.w);
    ((ushort4*)coreb)[i] = o;
}

// ---------------------------------------------------------------------------
// Kernel B: MFMA GEMM, no LDS, no barriers.
//   v[n,p] = sum_q u3[n,q] * core[p,q]   (A = u3b row-major, B = coreb row-major)
// Wave tile 32x32 (2x2 of 16x16x32 bf16). Block = 4 waves stacked in m.
// Grid (4096/128, 512/32) = (32,16) = 512 blocks, 2048 waves.
// Frags loaded straight from global (u3b 4MB + coreb 0.5MB: L2-resident).
// A-frag: lane holds row m0+(lane&15), k = (lane>>4)*8 + j   [m89/m91]
// B-frag: lane holds col p0+(lane&15), k = (lane>>4)*8 + j
// C/D:    col = lane&15, row = (lane>>4)*4 + reg             [m89]
// ---------------------------------------------------------------------------
__global__ __launch_bounds__(THREADS) void k_core_gemm_mfma(
    const unsigned short* __restrict__ u3b,
    const unsigned short* __restrict__ coreb,
    float* __restrict__ v, int N)
{
    const int t    = threadIdx.x;
    const int lane = t & 63;
    const int wave = t >> 6;
    const int m0 = blockIdx.x * 128 + wave * 32;
    const int p0 = blockIdx.y * 32;
    const int lr = lane & 15;
    const int lq = lane >> 4;

    const unsigned short* aptr0 = u3b   + (size_t)(m0 + lr) * 512 + lq * 8;
    const unsigned short* aptr1 = aptr0 + 16 * 512;
    const unsigned short* bptr0 = coreb + (size_t)(p0 + lr) * 512 + lq * 8;
    const unsigned short* bptr1 = bptr0 + 16 * 512;

    f32x4 acc00 = {0.f,0.f,0.f,0.f}, acc01 = {0.f,0.f,0.f,0.f};
    f32x4 acc10 = {0.f,0.f,0.f,0.f}, acc11 = {0.f,0.f,0.f,0.f};

    #pragma unroll
    for (int k0 = 0; k0 < 512; k0 += 32) {
        bf16x8 a0 = *(const bf16x8*)(aptr0 + k0);
        bf16x8 a1 = *(const bf16x8*)(aptr1 + k0);
        bf16x8 b0 = *(const bf16x8*)(bptr0 + k0);
        bf16x8 b1 = *(const bf16x8*)(bptr1 + k0);
        acc00 = __builtin_amdgcn_mfma_f32_16x16x32_bf16(a0, b0, acc00, 0, 0, 0);
        acc01 = __builtin_amdgcn_mfma_f32_16x16x32_bf16(a0, b1, acc01, 0, 0, 0);
        acc10 = __builtin_amdgcn_mfma_f32_16x16x32_bf16(a1, b0, acc10, 0, 0, 0);
        acc11 = __builtin_amdgcn_mfma_f32_16x16x32_bf16(a1, b1, acc11, 0, 0, 0);
    }

    const int row = m0 + lq * 4;
    const int col = p0 + lr;
    #pragma unroll
    for (int r = 0; r < 4; ++r) {
        v[(size_t)(row + r) * 512 + col]           = acc00[r];
        v[(size_t)(row + r) * 512 + col + 16]      = acc01[r];
        v[(size_t)(row + 16 + r) * 512 + col]      = acc10[r];
        v[(size_t)(row + 16 + r) * 512 + col + 16] = acc11[r];
    }
}

// ---------------------------------------------------------------------------
// Kernel C: out-side expansion  v[N,512] -> y[N,4096] (+bias)
// One block per batch row. (unchanged from round 1 -> want its counters)
// ---------------------------------------------------------------------------
__global__ __launch_bounds__(THREADS) void k_out_expand(
    const float* __restrict__ v,
    const float* __restrict__ f0, const float* __restrict__ f1,
    const float* __restrict__ f2, const float* __restrict__ bias,
    float* __restrict__ y, int N)
{
    const int n = blockIdx.x;
    const int t = threadIdx.x;

    __shared__ float fs[256];        // f0 [0..128) | f1 [128..256)
    __shared__ float vs[512];
    __shared__ float w1s[128 * 9];   // [a*8+j][k], pad 9
    __shared__ float w2s[256 * 9];   // [a*16+b][k], pad 9

    if (t < 128) { fs[t] = f0[t]; fs[128 + t] = f1[t]; }
    if (t < 128) ((float4*)vs)[t] = ((const float4*)(v + (size_t)n*512))[t];
    __syncthreads();

    // w1 stage: thread -> (a = t>>4, j = (t>>1)&7, h = t&1), k = 4h..4h+3
    {
        const int a = t >> 4, j = (t >> 1) & 7, h = t & 1;
        float fr[8];
        #pragma unroll
        for (int i = 0; i < 8; ++i) fr[i] = fs[a*8 + i];
        float a4[4] = {0.f, 0.f, 0.f, 0.f};
        #pragma unroll
        for (int i = 0; i < 8; ++i) {
            const int base = i*64 + j*8 + h*4;
            #pragma unroll
            for (int q = 0; q < 4; ++q)
                a4[q] = fmaf(vs[base + q], fr[i], a4[q]);
        }
        #pragma unroll
        for (int q = 0; q < 4; ++q) w1s[(a*8 + j)*9 + h*4 + q] = a4[q];
    }
    __syncthreads();

    // w2 stage: thread -> (a = t>>4, b = t&15), all k
    {
        const int a = t >> 4, b = t & 15;
        float fr[8];
        #pragma unroll
        for (int j = 0; j < 8; ++j) fr[j] = fs[128 + b*8 + j];
        float a8[8] = {0.f,0.f,0.f,0.f,0.f,0.f,0.f,0.f};
        #pragma unroll
        for (int j = 0; j < 8; ++j) {
            const int base = (a*8 + j)*9;
            const float fj = fr[j];
            #pragma unroll
            for (int k = 0; k < 8; ++k)
                a8[k] = fmaf(w1s[base + k], fj, a8[k]);
        }
        #pragma unroll
        for (int k = 0; k < 8; ++k) w2s[(a*16 + b)*9 + k] = a8[k];
    }
    __syncthreads();

    // y stage: thread -> (a = t>>4, b = t&15), c = 0..15
    {
        const int a = t >> 4, b = t & 15;
        float wr[8];
        #pragma unroll
        for (int k = 0; k < 8; ++k) wr[k] = w2s[(a*16 + b)*9 + k];

        const int obase = a*256 + b*16;   // == t*16
        float4 b4[4];
        {
            const float4* bp = (const float4*)(bias + obase);
            b4[0] = bp[0]; b4[1] = bp[1]; b4[2] = bp[2]; b4[3] = bp[3];
        }
        float yv[16];
        #pragma unroll
        for (int q = 0; q < 4; ++q) {
            yv[q*4+0] = b4[q].x; yv[q*4+1] = b4[q].y;
            yv[q*4+2] = b4[q].z; yv[q*4+3] = b4[q].w;
        }
        #pragma unroll
        for (int c = 0; c < 16; ++c) {
            float s = yv[c];
            #pragma unroll
            for (int k = 0; k < 8; ++k)
                s = fmaf(wr[k], f2[c*8 + k], s);   // f2 lane-uniform -> s_load
            yv[c] = s;
        }
        float4* o = (float4*)(y + (size_t)n*4096 + obase);
        #pragma unroll
        for (int q = 0; q < 4; ++q)
            o[q] = make_float4(yv[q*4+0], yv[q*4+1], yv[q*4+2], yv[q*4+3]);
    }
}

// ---------------------------------------------------------------------------
extern "C" void kernel_launch(void* const* d_in, const int* in_sizes, int n_in,
                              void* d_out, int out_size, void* d_ws, size_t ws_size,
                              hipStream_t stream)
{
    const float* x    = (const float*)d_in[0];
    const float* core = (const float*)d_in[1];
    const float* f0   = (const float*)d_in[2];
    const float* f1   = (const float*)d_in[3];
    const float* f2   = (const float*)d_in[4];
    const float* f3   = (const float*)d_in[5];
    const float* f4   = (const float*)d_in[6];
    const float* f5   = (const float*)d_in[7];
    const float* bias = (const float*)d_in[8];
    float* y = (float*)d_out;

    const int N = in_sizes[0] / 4096;

    // workspace: u3b bf16 [N,512] (4MB) | coreb bf16 [512,512] (0.5MB) | v fp32 [N,512] (8MB)
    unsigned short* u3b   = (unsigned short*)d_ws;
    unsigned short* coreb = u3b + (size_t)N * 512;
    float*          v     = (float*)(coreb + 512 * 512);

    k_in_contract<<<N, THREADS, 0, stream>>>(x, f3, f4, f5, u3b, N);
    k_convert_core<<<256, THREADS, 0, stream>>>(core, coreb);
    dim3 gb(N / 128, 512 / 32);
    k_core_gemm_mfma<<<gb, THREADS, 0, stream>>>(u3b, coreb, v, N);
    k_out_expand<<<N, THREADS, 0, stream>>>(v, f0, f1, f2, bias, y, N);
}